// Round 11
// baseline (53.389 us; speedup 1.0000x reference)
//
#include <hip/hip_runtime.h>
#include <hip/hip_cooperative_groups.h>

#define NPRE 32768
#define NPOST 32768
#define RR 64
#define BATCH 512
#define KSPLIT 128
#define KCHUNK 256  // NPRE / KSPLIT

namespace cg = cooperative_groups;

typedef float f32x4 __attribute__((ext_vector_type(4)));
typedef __bf16 bf16x8 __attribute__((ext_vector_type(8)));
typedef unsigned short u16;
typedef unsigned int u32;

static __device__ __forceinline__ u16 f2bfu(float f) {
  u32 u = __builtin_bit_cast(u32, f);
  return (u16)((u + 0x7fffu + ((u >> 16) & 1u)) >> 16);  // RNE round to bf16
}
static __device__ __forceinline__ __bf16 u2bf(u16 s) {
  return __builtin_bit_cast(__bf16, s);
}
static __device__ __forceinline__ float bf2f(u16 s) {
  return __builtin_bit_cast(float, (u32)s << 16);
}
static __device__ __forceinline__ bf16x8 cvt8(f32x4 lo, f32x4 hi) {
  bf16x8 b;
  b[0] = u2bf(f2bfu(lo.x)); b[1] = u2bf(f2bfu(lo.y));
  b[2] = u2bf(f2bfu(lo.z)); b[3] = u2bf(f2bfu(lo.w));
  b[4] = u2bf(f2bfu(hi.x)); b[5] = u2bf(f2bfu(hi.y));
  b[6] = u2bf(f2bfu(hi.z)); b[7] = u2bf(f2bfu(hi.w));
  return b;
}

// ---- Fused cooperative pipeline: 512 blocks x 512 thr (2 blocks/CU) -------
__global__ __launch_bounds__(512, 4) void fused(const float* __restrict__ S,
                                                const float* __restrict__ U,
                                                const float* __restrict__ V,
                                                u16* __restrict__ zp,
                                                u16* __restrict__ zb,
                                                float* __restrict__ y) {
  __shared__ u16 Ub[512 * 64];  // 64 KB (phase C)
  cg::grid_group grid = cg::this_grid();
  int bid = blockIdx.x;
  int t = threadIdx.x;
  int lane = t & 63;
  int w = t >> 6;  // 0..7
  int l15 = lane & 15, g = lane >> 4;

  // ---- Phase A: zp[kc][b][r] = S[b][kslice] @ V[kslice][r] ----------------
  {
    int eff = (bid & 7) * 64 + (bid >> 3);  // bijective XCD swizzle (512%8==0)
    int grp4 = eff & 3;
    int kc = eff >> 2;                      // 0..127, XCD-contiguous
    int mt = grp4 * 8 + w;                  // 0..31
    const float* A = S + (size_t)(mt * 16 + l15) * NPRE + kc * KCHUNK + g * 8;
    const float* Vb = V + (size_t)(kc * KCHUNK + g * 8) * RR + l15;
    f32x4 acc[4] = {};
#pragma unroll 2
    for (int ks = 0; ks < KCHUNK / 32; ++ks) {
      f32x4 a0 = __builtin_nontemporal_load(reinterpret_cast<const f32x4*>(A + ks * 32));
      f32x4 a1 = __builtin_nontemporal_load(reinterpret_cast<const f32x4*>(A + ks * 32 + 4));
      bf16x8 af = cvt8(a0, a1);
      const float* Vk = Vb + (size_t)ks * 32 * RR;
      bf16x8 bfr[4];
#pragma unroll
      for (int tt = 0; tt < 4; ++tt)
#pragma unroll
        for (int j = 0; j < 8; ++j)
          bfr[tt][j] = u2bf(f2bfu(Vk[j * RR + tt * 16]));
      acc[0] = __builtin_amdgcn_mfma_f32_16x16x32_bf16(af, bfr[0], acc[0], 0, 0, 0);
      acc[1] = __builtin_amdgcn_mfma_f32_16x16x32_bf16(af, bfr[1], acc[1], 0, 0, 0);
      acc[2] = __builtin_amdgcn_mfma_f32_16x16x32_bf16(af, bfr[2], acc[2], 0, 0, 0);
      acc[3] = __builtin_amdgcn_mfma_f32_16x16x32_bf16(af, bfr[3], acc[3], 0, 0, 0);
    }
    u16* out = zp + ((size_t)kc * BATCH + mt * 16) * RR;
#pragma unroll
    for (int tt = 0; tt < 4; ++tt)
#pragma unroll
      for (int q = 0; q < 4; ++q)
        out[(g * 4 + q) * RR + tt * 16 + l15] = f2bfu(acc[tt][q]);
  }
  grid.sync();

  // ---- Phase B: zb[i] = sum_k zp[k][i] ------------------------------------
  {
    int i = bid * 64 + (t >> 3);            // 512*64 = 32768 outputs
    int sub = t & 7;
    const u16* p = zp + (size_t)sub * (BATCH * RR) + i;
    float s0 = 0.f, s1 = 0.f;
#pragma unroll
    for (int j = 0; j < 16; j += 2) {
      s0 += bf2f(p[(size_t)(8 * j) * (BATCH * RR)]);
      s1 += bf2f(p[(size_t)(8 * (j + 1)) * (BATCH * RR)]);
    }
    float s = s0 + s1;
    s += __shfl_xor(s, 1);
    s += __shfl_xor(s, 2);
    s += __shfl_xor(s, 4);
    if (sub == 0) zb[i] = f2bfu(s);
  }
  grid.sync();

  // ---- Phase C: y = z @ U^T (streaming, v4-form to cut VGPRs) -------------
  {
    int eff = (bid & 7) * 64 + (bid >> 3);
    int nt = eff >> 3;
    int bg = eff & 7;
    int n0 = nt * 512;
    char* Uc = reinterpret_cast<char*>(Ub);
#pragma unroll
    for (int i = 0; i < 16; ++i) {
      int f = i * 2048 + t * 4;
      int row = f >> 6;
      int colb = (f & 63) * 2;
      f32x4 u = *reinterpret_cast<const f32x4*>(U + (size_t)n0 * RR + f);
      uint2 pk;
      pk.x = (u32)f2bfu(u.x) | ((u32)f2bfu(u.y) << 16);
      pk.y = (u32)f2bfu(u.z) | ((u32)f2bfu(u.w) << 16);
      *reinterpret_cast<uint2*>(Uc + ((row * 128 + colb) ^ ((row & 7) << 4))) = pk;
    }
    __syncthreads();

#pragma unroll
    for (int it = 0; it < 4; ++it) {
      int b0 = bg * 64 + it * 16;
      const u16* A = zb + (size_t)(b0 + l15) * RR + g * 8;
      bf16x8 z0 = *reinterpret_cast<const bf16x8*>(A);
      bf16x8 z1 = *reinterpret_cast<const bf16x8*>(A + 32);
      f32x4 acc[4] = {};
#pragma unroll
      for (int j = 0; j < 4; ++j) {
        int tau = w + 8 * j;
        int row = tau * 16 + l15;
        int base = row * 128;
        int swz = (row & 7) << 4;
        bf16x8 uA = *reinterpret_cast<const bf16x8*>(Uc + ((base + g * 16) ^ swz));
        bf16x8 uB = *reinterpret_cast<const bf16x8*>(Uc + ((base + 64 + g * 16) ^ swz));
        acc[j] = __builtin_amdgcn_mfma_f32_16x16x32_bf16(uA, z0, acc[j], 0, 0, 0);
        acc[j] = __builtin_amdgcn_mfma_f32_16x16x32_bf16(uB, z1, acc[j], 0, 0, 0);
      }
      float* yb = y + (size_t)(b0 + l15) * NPOST + n0;
#pragma unroll
      for (int j = 0; j < 4; ++j) {
        int tau = w + 8 * j;
        *reinterpret_cast<f32x4*>(yb + tau * 16 + g * 4) = acc[j];
      }
    }
  }
}

// ---- Fallback 3-kernel path (round-9, known-good 53 us) -------------------
__global__ __launch_bounds__(256, 4) void k1(const float* __restrict__ S,
                                             const float* __restrict__ V,
                                             u16* __restrict__ zp) {
  int bid = blockIdx.x;
  int eff = (bid & 7) * 128 + (bid >> 3);
  int grp = eff & 7;
  int kc = eff >> 3;
  int lane = threadIdx.x & 63;
  int w = threadIdx.x >> 6;
  int mt = grp * 4 + w;
  int l15 = lane & 15, g = lane >> 4;
  const float* A = S + (size_t)(mt * 16 + l15) * NPRE + kc * KCHUNK + g * 8;
  const float* Vb = V + (size_t)(kc * KCHUNK + g * 8) * RR + l15;
  f32x4 acc[4] = {};
#pragma unroll 2
  for (int ks = 0; ks < KCHUNK / 32; ++ks) {
    f32x4 a0 = __builtin_nontemporal_load(reinterpret_cast<const f32x4*>(A + ks * 32));
    f32x4 a1 = __builtin_nontemporal_load(reinterpret_cast<const f32x4*>(A + ks * 32 + 4));
    bf16x8 af = cvt8(a0, a1);
    const float* Vk = Vb + (size_t)ks * 32 * RR;
    bf16x8 bfr[4];
#pragma unroll
    for (int tt = 0; tt < 4; ++tt)
#pragma unroll
      for (int j = 0; j < 8; ++j)
        bfr[tt][j] = u2bf(f2bfu(Vk[j * RR + tt * 16]));
    acc[0] = __builtin_amdgcn_mfma_f32_16x16x32_bf16(af, bfr[0], acc[0], 0, 0, 0);
    acc[1] = __builtin_amdgcn_mfma_f32_16x16x32_bf16(af, bfr[1], acc[1], 0, 0, 0);
    acc[2] = __builtin_amdgcn_mfma_f32_16x16x32_bf16(af, bfr[2], acc[2], 0, 0, 0);
    acc[3] = __builtin_amdgcn_mfma_f32_16x16x32_bf16(af, bfr[3], acc[3], 0, 0, 0);
  }
  u16* out = zp + ((size_t)kc * BATCH + mt * 16) * RR;
#pragma unroll
  for (int tt = 0; tt < 4; ++tt)
#pragma unroll
    for (int q = 0; q < 4; ++q)
      out[(g * 4 + q) * RR + tt * 16 + l15] = f2bfu(acc[tt][q]);
}

__global__ __launch_bounds__(1024) void k_red(const u16* __restrict__ zp,
                                              u16* __restrict__ zb) {
  __shared__ float part[4][256];
  int il = threadIdx.x & 255;
  int tg = threadIdx.x >> 8;
  int i = blockIdx.x * 256 + il;
  const u16* p = zp + (size_t)tg * 32 * (BATCH * RR) + i;
  float s0 = 0.f, s1 = 0.f, s2 = 0.f, s3 = 0.f;
#pragma unroll
  for (int t = 0; t < 32; t += 4) {
    s0 += bf2f(p[(size_t)(t + 0) * (BATCH * RR)]);
    s1 += bf2f(p[(size_t)(t + 1) * (BATCH * RR)]);
    s2 += bf2f(p[(size_t)(t + 2) * (BATCH * RR)]);
    s3 += bf2f(p[(size_t)(t + 3) * (BATCH * RR)]);
  }
  part[tg][il] = (s0 + s1) + (s2 + s3);
  __syncthreads();
  if (tg == 0)
    zb[i] = f2bfu((part[0][il] + part[1][il]) + (part[2][il] + part[3][il]));
}

__global__ __launch_bounds__(512, 4) void k2(const u16* __restrict__ zb,
                                             const float* __restrict__ U,
                                             float* __restrict__ y) {
  __shared__ u16 Ub[512 * 64];
  int bid = blockIdx.x;
  int eff = (bid & 7) * 64 + (bid >> 3);
  int nt = eff >> 3;
  int bg = eff & 7;
  int n0 = nt * 512;
  int t = threadIdx.x;
  int lane = t & 63;
  int w = t >> 6;
  int l15 = lane & 15, g = lane >> 4;
  char* Uc = reinterpret_cast<char*>(Ub);
#pragma unroll
  for (int i = 0; i < 16; ++i) {
    int f = i * 2048 + t * 4;
    int row = f >> 6;
    int colb = (f & 63) * 2;
    f32x4 u = *reinterpret_cast<const f32x4*>(U + (size_t)n0 * RR + f);
    uint2 pk;
    pk.x = (u32)f2bfu(u.x) | ((u32)f2bfu(u.y) << 16);
    pk.y = (u32)f2bfu(u.z) | ((u32)f2bfu(u.w) << 16);
    *reinterpret_cast<uint2*>(Uc + ((row * 128 + colb) ^ ((row & 7) << 4))) = pk;
  }
  __syncthreads();
#pragma unroll
  for (int it = 0; it < 4; ++it) {
    int b0 = bg * 64 + it * 16;
    const u16* A = zb + (size_t)(b0 + l15) * RR + g * 8;
    bf16x8 z0 = *reinterpret_cast<const bf16x8*>(A);
    bf16x8 z1 = *reinterpret_cast<const bf16x8*>(A + 32);
    f32x4 acc[4] = {};
#pragma unroll
    for (int j = 0; j < 4; ++j) {
      int tau = w + 8 * j;
      int row = tau * 16 + l15;
      int base = row * 128;
      int swz = (row & 7) << 4;
      bf16x8 uA = *reinterpret_cast<const bf16x8*>(Uc + ((base + g * 16) ^ swz));
      bf16x8 uB = *reinterpret_cast<const bf16x8*>(Uc + ((base + 64 + g * 16) ^ swz));
      acc[j] = __builtin_amdgcn_mfma_f32_16x16x32_bf16(uA, z0, acc[j], 0, 0, 0);
      acc[j] = __builtin_amdgcn_mfma_f32_16x16x32_bf16(uB, z1, acc[j], 0, 0, 0);
    }
    float* yb = y + (size_t)(b0 + l15) * NPOST + n0;
#pragma unroll
    for (int j = 0; j < 4; ++j) {
      int tau = w + 8 * j;
      *reinterpret_cast<f32x4*>(yb + tau * 16 + g * 4) = acc[j];
    }
  }
}

extern "C" void kernel_launch(void* const* d_in, const int* in_sizes, int n_in,
                              void* d_out, int out_size, void* d_ws, size_t ws_size,
                              hipStream_t stream) {
  const float* spikes = (const float*)d_in[0];
  const float* U = (const float*)d_in[1];
  const float* V = (const float*)d_in[2];
  // d_in[3..5]: CSR mask — dead in the reference, unused.
  float* y = (float*)d_out;
  char* ws = (char*)d_ws;
  u16* zp = (u16*)ws;                    // 8 MiB  [KSPLIT][BATCH][RR] bf16
  u16* zb = (u16*)(ws + (8u << 20));     // 64 KiB [BATCH][RR] bf16

  // Occupancy-gated cooperative launch (host-side queries: capture-safe,
  // deterministic). Fall back to the known-good 3-kernel path otherwise.
  int dev = 0;
  (void)hipGetDevice(&dev);
  int ncu = 0;
  (void)hipDeviceGetAttribute(&ncu, hipDeviceAttributeMultiprocessorCount, dev);
  int nb = 0;
  hipError_t qe =
      hipOccupancyMaxActiveBlocksPerMultiprocessor(&nb, (const void*)fused, 512, 0);
  if (qe == hipSuccess && (long)nb * (long)ncu >= 512) {
    void* args[] = {(void*)&spikes, (void*)&U, (void*)&V,
                    (void*)&zp, (void*)&zb, (void*)&y};
    if (hipLaunchCooperativeKernel((const void*)fused, dim3(512), dim3(512),
                                   args, 0, stream) == hipSuccess)
      return;
  }
  k1<<<1024, 256, 0, stream>>>(spikes, V, zp);
  k_red<<<128, 1024, 0, stream>>>(zp, zb);
  k2<<<512, 512, 0, stream>>>(zb, U, y);
}

// Round 12
// 45.208 us; speedup vs baseline: 1.1809x; 1.1809x over previous
//
#include <hip/hip_runtime.h>

#define NPRE 32768
#define NPOST 32768
#define RR 64
#define BATCH 512
#define KSPLIT 128
#define KCHUNK 256  // NPRE / KSPLIT

typedef float f32x4 __attribute__((ext_vector_type(4)));
typedef __bf16 bf16x8 __attribute__((ext_vector_type(8)));
typedef unsigned short u16;
typedef unsigned int u32;

static __device__ __forceinline__ u16 f2bfu(float f) {
  u32 u = __builtin_bit_cast(u32, f);
  return (u16)((u + 0x7fffu + ((u >> 16) & 1u)) >> 16);  // RNE round to bf16
}
static __device__ __forceinline__ __bf16 u2bf(u16 s) {
  return __builtin_bit_cast(__bf16, s);
}
static __device__ __forceinline__ float bf2f(u16 s) {
  return __builtin_bit_cast(float, (u32)s << 16);
}
// HW packed f32->bf16 (RNE): 1 VALU op for 2 elements. No builtin on gfx950.
static __device__ __forceinline__ u32 cvtpk(float lo, float hi) {
  u32 r;
  asm("v_cvt_pk_bf16_f32 %0, %1, %2" : "=v"(r) : "v"(lo), "v"(hi));
  return r;
}
static __device__ __forceinline__ bf16x8 pack8(f32x4 lo, f32x4 hi) {
  union { u32 w[4]; bf16x8 v; } u;
  u.w[0] = cvtpk(lo.x, lo.y);
  u.w[1] = cvtpk(lo.z, lo.w);
  u.w[2] = cvtpk(hi.x, hi.y);
  u.w[3] = cvtpk(hi.z, hi.w);
  return u.v;
}
static __device__ __forceinline__ bf16x8 cvt8(f32x4 lo, f32x4 hi) {  // k2 path (unchanged)
  bf16x8 b;
  b[0] = u2bf(f2bfu(lo.x)); b[1] = u2bf(f2bfu(lo.y));
  b[2] = u2bf(f2bfu(lo.z)); b[3] = u2bf(f2bfu(lo.w));
  b[4] = u2bf(f2bfu(hi.x)); b[5] = u2bf(f2bfu(hi.y));
  b[6] = u2bf(f2bfu(hi.z)); b[7] = u2bf(f2bfu(hi.w));
  return b;
}

// ---- GEMM1 v2: cvt_pk conversions + cached (non-nt) spikes loads ----------
// Theory: k1 was VALU-issue-bound (~150-200 VALU/iter for f32->bf16 repack vs
// 4 MFMA). cvt_pk cuts that to ~16; dropping nt lets 64MB spikes stay
// L3-resident across replays (fused-run FETCH=45.8MB proved partial residency).
__global__ __launch_bounds__(256, 4) void k1(const float* __restrict__ S,
                                             const float* __restrict__ V,
                                             u16* __restrict__ zp) {
  int bid = blockIdx.x;
  int eff = (bid & 7) * 128 + (bid >> 3);  // bijective XCD swizzle (1024 % 8 == 0)
  int grp = eff & 7;
  int kc = eff >> 3;                       // XCD-contiguous kc range
  int lane = threadIdx.x & 63;
  int w = threadIdx.x >> 6;
  int mt = grp * 4 + w;                    // 0..31
  int l15 = lane & 15, g = lane >> 4;
  const float* A = S + (size_t)(mt * 16 + l15) * NPRE + kc * KCHUNK + g * 8;
  const float* Vb = V + (size_t)(kc * KCHUNK + g * 8) * RR + l15;
  f32x4 acc[4] = {};
#pragma unroll 2
  for (int ks = 0; ks < KCHUNK / 32; ++ks) {
    f32x4 a0 = *reinterpret_cast<const f32x4*>(A + ks * 32);
    f32x4 a1 = *reinterpret_cast<const f32x4*>(A + ks * 32 + 4);
    bf16x8 af = pack8(a0, a1);
    const float* Vk = Vb + (size_t)ks * 32 * RR;
    bf16x8 bfr[4];
#pragma unroll
    for (int tt = 0; tt < 4; ++tt) {
      f32x4 lo, hi;
      lo.x = Vk[0 * RR + tt * 16]; lo.y = Vk[1 * RR + tt * 16];
      lo.z = Vk[2 * RR + tt * 16]; lo.w = Vk[3 * RR + tt * 16];
      hi.x = Vk[4 * RR + tt * 16]; hi.y = Vk[5 * RR + tt * 16];
      hi.z = Vk[6 * RR + tt * 16]; hi.w = Vk[7 * RR + tt * 16];
      bfr[tt] = pack8(lo, hi);
    }
    acc[0] = __builtin_amdgcn_mfma_f32_16x16x32_bf16(af, bfr[0], acc[0], 0, 0, 0);
    acc[1] = __builtin_amdgcn_mfma_f32_16x16x32_bf16(af, bfr[1], acc[1], 0, 0, 0);
    acc[2] = __builtin_amdgcn_mfma_f32_16x16x32_bf16(af, bfr[2], acc[2], 0, 0, 0);
    acc[3] = __builtin_amdgcn_mfma_f32_16x16x32_bf16(af, bfr[3], acc[3], 0, 0, 0);
  }
  // D layout: col = lane&15 (B-lane space), row = (lane>>4)*4 + reg (A-lane space)
  u16* out = zp + ((size_t)kc * BATCH + mt * 16) * RR;
#pragma unroll
  for (int tt = 0; tt < 4; ++tt)
#pragma unroll
    for (int q = 0; q < 4; ++q)
      out[(g * 4 + q) * RR + tt * 16 + l15] = (u16)cvtpk(acc[tt][q], acc[tt][q]);
}

// ---- reduce 128 bf16 partials -> z bf16 [BATCH][RR] (frozen) --------------
__global__ __launch_bounds__(1024) void k_red(const u16* __restrict__ zp,
                                              u16* __restrict__ zb) {
  __shared__ float part[4][256];
  int il = threadIdx.x & 255;
  int tg = threadIdx.x >> 8;
  int i = blockIdx.x * 256 + il;
  const u16* p = zp + (size_t)tg * 32 * (BATCH * RR) + i;
  float s0 = 0.f, s1 = 0.f, s2 = 0.f, s3 = 0.f;
#pragma unroll
  for (int t = 0; t < 32; t += 4) {
    s0 += bf2f(p[(size_t)(t + 0) * (BATCH * RR)]);
    s1 += bf2f(p[(size_t)(t + 1) * (BATCH * RR)]);
    s2 += bf2f(p[(size_t)(t + 2) * (BATCH * RR)]);
    s3 += bf2f(p[(size_t)(t + 3) * (BATCH * RR)]);
  }
  part[tg][il] = (s0 + s1) + (s2 + s3);
  __syncthreads();
  if (tg == 0)
    zb[i] = f2bfu((part[0][il] + part[1][il]) + (part[2][il] + part[3][il]));
}

// ---- GEMM2 (frozen, r10-fallback form): y = z @ U^T -----------------------
__global__ __launch_bounds__(512, 4) void k2(const u16* __restrict__ zb,
                                             const float* __restrict__ U,
                                             float* __restrict__ y) {
  __shared__ u16 Ub[512 * 64];
  int bid = blockIdx.x;
  int eff = (bid & 7) * 64 + (bid >> 3);
  int nt = eff >> 3;
  int bg = eff & 7;
  int n0 = nt * 512;
  int t = threadIdx.x;
  int lane = t & 63;
  int w = t >> 6;
  int l15 = lane & 15, g = lane >> 4;
  char* Uc = reinterpret_cast<char*>(Ub);
#pragma unroll
  for (int i = 0; i < 16; ++i) {
    int f = i * 2048 + t * 4;
    int row = f >> 6;
    int colb = (f & 63) * 2;
    f32x4 u = *reinterpret_cast<const f32x4*>(U + (size_t)n0 * RR + f);
    uint2 pk;
    pk.x = (u32)f2bfu(u.x) | ((u32)f2bfu(u.y) << 16);
    pk.y = (u32)f2bfu(u.z) | ((u32)f2bfu(u.w) << 16);
    *reinterpret_cast<uint2*>(Uc + ((row * 128 + colb) ^ ((row & 7) << 4))) = pk;
  }
  __syncthreads();
#pragma unroll
  for (int it = 0; it < 4; ++it) {
    int b0 = bg * 64 + it * 16;
    const u16* A = zb + (size_t)(b0 + l15) * RR + g * 8;
    bf16x8 z0 = *reinterpret_cast<const bf16x8*>(A);
    bf16x8 z1 = *reinterpret_cast<const bf16x8*>(A + 32);
    f32x4 acc[4] = {};
#pragma unroll
    for (int j = 0; j < 4; ++j) {
      int tau = w + 8 * j;
      int row = tau * 16 + l15;
      int base = row * 128;
      int swz = (row & 7) << 4;
      bf16x8 uA = *reinterpret_cast<const bf16x8*>(Uc + ((base + g * 16) ^ swz));
      bf16x8 uB = *reinterpret_cast<const bf16x8*>(Uc + ((base + 64 + g * 16) ^ swz));
      acc[j] = __builtin_amdgcn_mfma_f32_16x16x32_bf16(uA, z0, acc[j], 0, 0, 0);
      acc[j] = __builtin_amdgcn_mfma_f32_16x16x32_bf16(uB, z1, acc[j], 0, 0, 0);
    }
    float* yb = y + (size_t)(b0 + l15) * NPOST + n0;
#pragma unroll
    for (int j = 0; j < 4; ++j) {
      int tau = w + 8 * j;
      *reinterpret_cast<f32x4*>(yb + tau * 16 + g * 4) = acc[j];
    }
  }
}

extern "C" void kernel_launch(void* const* d_in, const int* in_sizes, int n_in,
                              void* d_out, int out_size, void* d_ws, size_t ws_size,
                              hipStream_t stream) {
  const float* spikes = (const float*)d_in[0];
  const float* U = (const float*)d_in[1];
  const float* V = (const float*)d_in[2];
  // d_in[3..5]: CSR mask — dead in the reference, unused.
  float* y = (float*)d_out;
  char* ws = (char*)d_ws;
  u16* zp = (u16*)ws;                    // 8 MiB  [KSPLIT][BATCH][RR] bf16
  u16* zb = (u16*)(ws + (8u << 20));     // 64 KiB [BATCH][RR] bf16

  k1<<<1024, 256, 0, stream>>>(spikes, V, zp);
  k_red<<<128, 1024, 0, stream>>>(zp, zb);
  k2<<<512, 512, 0, stream>>>(zb, U, y);
}